// Round 1
// baseline (677.612 us; speedup 1.0000x reference)
//
#include <hip/hip_runtime.h>

typedef unsigned short ushort_t;
typedef __attribute__((ext_vector_type(4))) unsigned short ushort4_t;
typedef __attribute__((ext_vector_type(8))) unsigned short ushort8;
typedef __attribute__((ext_vector_type(8))) __bf16 bf16x8;
typedef __attribute__((ext_vector_type(4))) float f32x4;

typedef const unsigned int __attribute__((address_space(1)))* gas_ptr;
typedef unsigned int __attribute__((address_space(3)))* las_ptr;

__device__ __forceinline__ float b2f(unsigned short u) {
    union { unsigned int i; float f; } x; x.i = ((unsigned int)u) << 16; return x.f;
}
__device__ __forceinline__ unsigned short f2b(float f) {
    union { float f; unsigned int i; } x; x.f = f;
    unsigned int r = (x.i + 0x7fffu + ((x.i >> 16) & 1u)) >> 16;  // RNE
    return (unsigned short)r;
}

// ---------------- fp32 -> bf16 convert, all three weight mats in one launch ----------------
__global__ __launch_bounds__(256) void cvt_kernel(const float* __restrict__ wq,
        const float* __restrict__ wkv, const float* __restrict__ wo,
        ushort_t* __restrict__ yq, ushort_t* __restrict__ ykv, ushort_t* __restrict__ yo) {
    int b = blockIdx.x;
    const float* x; ushort_t* y; size_t off;
    if (b < 1024)      { x = wq;  y = yq;  off = (size_t)b * 1024; }
    else if (b < 3072) { x = wkv; y = ykv; off = (size_t)(b - 1024) * 1024; }
    else               { x = wo;  y = yo;  off = (size_t)(b - 3072) * 1024; }
    size_t i = off + threadIdx.x * 4;
    f32x4 v = *(const f32x4*)(x + i);
    ushort4_t o;
    #pragma unroll
    for (int t = 0; t < 4; ++t) o[t] = f2b(v[t]);
    *(ushort4_t*)(y + i) = o;
}

// ---------------- LayerNorm: one wave per 1024-elem row, fp32 in -> bf16 out ----------------
__global__ __launch_bounds__(256) void ln_kernel(const float* __restrict__ x,
        const float* __restrict__ gamma, const float* __restrict__ beta,
        ushort_t* __restrict__ y) {
    int wave = threadIdx.x >> 6, lane = threadIdx.x & 63;
    size_t row = (size_t)blockIdx.x * 4 + wave;
    const float* xr = x + row * 1024;
    f32x4 v[4];
    #pragma unroll
    for (int c = 0; c < 4; ++c) v[c] = *(const f32x4*)(xr + c * 256 + lane * 4);
    float s = 0.f, s2 = 0.f;
    #pragma unroll
    for (int c = 0; c < 4; ++c)
        #pragma unroll
        for (int t = 0; t < 4; ++t) { s += v[c][t]; s2 += v[c][t] * v[c][t]; }
    #pragma unroll
    for (int off = 1; off < 64; off <<= 1) {
        s  += __shfl_xor(s,  off, 64);
        s2 += __shfl_xor(s2, off, 64);
    }
    float mean = s * (1.0f / 1024.0f);
    float var  = fmaxf(s2 * (1.0f / 1024.0f) - mean * mean, 0.f);
    float rstd = rsqrtf(var + 1e-5f);
    ushort_t* yr = y + row * 1024;
    #pragma unroll
    for (int c = 0; c < 4; ++c) {
        f32x4 g = *(const f32x4*)(gamma + c * 256 + lane * 4);
        f32x4 b = *(const f32x4*)(beta  + c * 256 + lane * 4);
        ushort4_t o;
        #pragma unroll
        for (int t = 0; t < 4; ++t)
            o[t] = f2b((v[c][t] - mean) * rstd * g[t] + b[t]);
        *(ushort4_t*)(yr + c * 256 + lane * 4) = o;
    }
}

// ================== 256x256 8-phase GEMM: C[M,N] = A[M,K] * B[N,K]^T ==================
// Port of the verified 8-phase template (T2+T3+T4+T5): BM=BN=256, BK=64, 512 thr (8 waves
// as 2Mx4N, each owns a 128x64 output = acc[8][4] f32x4). LDS = 2 buffers x (A[256][64] +
// B[256][64]) bf16 = 128 KiB.
//
// LDS swizzle (T2): element (row,col) of a [*][64] tile is stored at row*64 +
// (col ^ ((row&7)<<3)) -> a wave's 16-lanes-same-column ds_read_b128 spreads over 8
// distinct 16B slots (2-way = free) instead of 16-way. global_load_lds writes linearly,
// so the swizzle is realized by pre-swizzling the per-lane GLOBAL source column
// (both-sides-or-neither).
//
// Schedule per K-tile t (buf c = t&1), 4 phases; stage unit = 64 rows x 64 cols = 1
// global_load_lds(16B)/thread; region liveness proven by read-retirement:
//   P0: stage A[64-127],A[192-255] of tile t+1 -> buf c^1 ; read A(qm=0)+B(qn=0) ; MFMA Q00
//   P1: stage B[128-191],B[192-255] of tile t+1 -> buf c^1 ; read B(qn=1)       ; MFMA Q01
//   P2: stage A[0-63],  A[128-191] of tile t+2 -> buf c   ; read A(qm=1)       ; MFMA Q10
//       (A qm=0 rows {0-63,128-191} were last read in P0 -> retired; safe to overwrite)
//   P3: stage B[0-63],  B[64-127]  of tile t+2 -> buf c   ; vmcnt(4)           ; MFMA Q11
//       (all B rows retired after P1)
// Each phase: stages+reads -> s_barrier -> lgkmcnt(0) -> setprio(1) -> 16 MFMA ->
// setprio(0) -> s_barrier. One counted s_waitcnt vmcnt(4) per K-tile: at that point
// outstanding = 4 (leftover t+1 u0-3) + 8 (this tile) = 12, waits 8 oldest -> tile t+1
// fully landed, tile t+2's first 4 units stay in flight across the barrier (never
// drains to 0 in the loop). Tail: staged kt is clamped to K-64 (redundant L2-hit
// restage) so the per-wave vmcnt count stays exact -- skipping stages would turn
// vmcnt(4) into a no-wait race.
// Prologue: tile0 (8 units) -> buf0, tile1 u0-3 -> buf1, vmcnt(4), barrier. Needs K>=128.

#define STG_A(BUFB, RBASE, KT) \
    __builtin_amdgcn_global_load_lds((gas_ptr)(Ap + (size_t)(RBASE) * K + (KT)), \
        (las_ptr)(lds + (BUFB) * 32768 + (RBASE) * 64 + tid * 8), 16, 0, 0)
#define STG_B(BUFB, RBASE, KT) \
    __builtin_amdgcn_global_load_lds((gas_ptr)(Bp + (size_t)(RBASE) * K + (KT)), \
        (las_ptr)(lds + (BUFB) * 32768 + 16384 + (RBASE) * 64 + tid * 8), 16, 0, 0)

#define RD_A(CB, QM) do { _Pragma("unroll") \
    for (int fm = 0; fm < 4; ++fm) { \
        a[fm][0] = *(const bf16x8*)(lds + (CB) * 32768 + aB + (QM) * 4096 + fm * 1024 + ce0); \
        a[fm][1] = *(const bf16x8*)(lds + (CB) * 32768 + aB + (QM) * 4096 + fm * 1024 + ce1); \
    } } while (0)
#define RD_B(CB, QN, BV) do { _Pragma("unroll") \
    for (int fn = 0; fn < 2; ++fn) { \
        BV[fn][0] = *(const bf16x8*)(lds + (CB) * 32768 + bB + (QN) * 2048 + fn * 1024 + ce0); \
        BV[fn][1] = *(const bf16x8*)(lds + (CB) * 32768 + bB + (QN) * 2048 + fn * 1024 + ce1); \
    } } while (0)

#define MFMA_Q(QM, QN, BV) do { _Pragma("unroll") \
    for (int fm = 0; fm < 4; ++fm) { _Pragma("unroll") \
        for (int fn = 0; fn < 2; ++fn) { \
            acc[(QM) * 4 + fm][(QN) * 2 + fn] = __builtin_amdgcn_mfma_f32_16x16x32_bf16( \
                a[fm][0], BV[fn][0], acc[(QM) * 4 + fm][(QN) * 2 + fn], 0, 0, 0); \
            acc[(QM) * 4 + fm][(QN) * 2 + fn] = __builtin_amdgcn_mfma_f32_16x16x32_bf16( \
                a[fm][1], BV[fn][1], acc[(QM) * 4 + fm][(QN) * 2 + fn], 0, 0, 0); \
    } } } while (0)

#define PH_PRE() do { __builtin_amdgcn_s_barrier(); \
    asm volatile("s_waitcnt lgkmcnt(0)" ::: "memory"); \
    __builtin_amdgcn_s_setprio(1); } while (0)
#define PH_POST() do { __builtin_amdgcn_s_setprio(0); \
    __builtin_amdgcn_s_barrier(); } while (0)

#define KTILE(CB, KTN, KTNN) do { \
    /* P0 */ \
    STG_A((CB) ^ 1, 64, KTN); STG_A((CB) ^ 1, 192, KTN); \
    RD_A(CB, 0); RD_B(CB, 0, b0); \
    PH_PRE(); MFMA_Q(0, 0, b0); PH_POST(); \
    /* P1 */ \
    STG_B((CB) ^ 1, 128, KTN); STG_B((CB) ^ 1, 192, KTN); \
    RD_B(CB, 1, b1); \
    PH_PRE(); MFMA_Q(0, 1, b1); PH_POST(); \
    /* P2 */ \
    STG_A(CB, 0, KTNN); STG_A(CB, 128, KTNN); \
    RD_A(CB, 1); \
    PH_PRE(); MFMA_Q(1, 0, b0); PH_POST(); \
    /* P3 */ \
    STG_B(CB, 0, KTNN); STG_B(CB, 64, KTNN); \
    asm volatile("s_waitcnt vmcnt(4)" ::: "memory"); \
    PH_PRE(); MFMA_Q(1, 1, b1); PH_POST(); \
} while (0)

template <bool OUT_F32>
__global__ __launch_bounds__(512) void gemm256(const ushort_t* __restrict__ A,
        const ushort_t* __restrict__ B, void* __restrict__ Cv,
        int M, int N, int K) {
    __shared__ ushort_t lds[65536];   // 128 KiB
    const int tid = threadIdx.x;
    const int lane = tid & 63;
    const int wid = tid >> 6;
    const int wr = wid >> 2, wc = wid & 3;           // 2 (M) x 4 (N) wave grid
    const int r16 = lane & 15, q4 = lane >> 4;
    const int m0 = blockIdx.y * 256, n0 = blockIdx.x * 256;
    const int NT = K >> 6;

    // staging: thread handles one 16B chunk per unit; source col pre-swizzled
    const int rA = tid >> 3;                               // 0..63 within a unit
    const int cS = ((tid & 7) * 8) ^ ((rA & 7) * 8);       // inverse-swizzled src col
    const ushort_t* Ap = A + (size_t)(m0 + rA) * K + cS;
    const ushort_t* Bp = B + (size_t)(n0 + rA) * K + cS;

    // read-side swizzled column offsets (row&7 == lane&7 for every fragment row)
    const int ce0 = (q4 * 8) ^ ((lane & 7) * 8);           // kk=0
    const int ce1 = ce0 ^ 32;                              // kk=1
    const int aB = (wr * 128 + r16) * 64;                  // + qm*4096 + fm*1024
    const int bB = 16384 + (wc * 64 + r16) * 64;           // + qn*2048 + fn*1024

    f32x4 acc[8][4];
    #pragma unroll
    for (int i = 0; i < 8; ++i)
        #pragma unroll
        for (int j = 0; j < 4; ++j)
            acc[i][j] = (f32x4){0.f, 0.f, 0.f, 0.f};
    bf16x8 a[4][2], b0[2][2], b1[2][2];

    // prologue: tile0 (all 8 units) -> buf0 first (oldest), then tile1 u0-3 -> buf1
    STG_A(0, 0, 0); STG_A(0, 128, 0); STG_B(0, 0, 0); STG_B(0, 64, 0);
    STG_A(0, 64, 0); STG_A(0, 192, 0); STG_B(0, 128, 0); STG_B(0, 192, 0);
    STG_A(1, 0, 64); STG_A(1, 128, 64); STG_B(1, 0, 64); STG_B(1, 64, 64);
    asm volatile("s_waitcnt vmcnt(4)" ::: "memory");       // tile0 landed, tile1 u0-3 in flight
    __builtin_amdgcn_s_barrier();

    for (int tt = 0; tt < (NT >> 1); ++tt) {
        const int t = tt << 1;
        const int k1 = (t + 1) << 6;                       // always < K
        int k2 = (t + 2) << 6; if (k2 > K - 64) k2 = K - 64;
        int k3 = (t + 3) << 6; if (k3 > K - 64) k3 = K - 64;
        KTILE(0, k1, k2);
        KTILE(1, k2, k3);
    }

    // C/D: col = lane&15, row = (lane>>4)*4 + reg
    #pragma unroll
    for (int fm = 0; fm < 8; ++fm) {
        #pragma unroll
        for (int rr = 0; rr < 4; ++rr) {
            int rowC = m0 + wr * 128 + fm * 16 + q4 * 4 + rr;
            if (OUT_F32) {
                float* Cr = (float*)Cv + (size_t)rowC * N + n0 + wc * 64 + r16;
                #pragma unroll
                for (int fn = 0; fn < 4; ++fn)
                    Cr[fn * 16] = acc[fm][fn][rr];
            } else {
                ushort_t* Cr = (ushort_t*)Cv + (size_t)rowC * N + n0 + wc * 64 + r16;
                #pragma unroll
                for (int fn = 0; fn < 4; ++fn)
                    Cr[fn * 16] = f2b(acc[fm][fn][rr]);
            }
        }
    }
}

// ---------------- per-position 8x8 attention, one wave per position ----------------
// out may alias qin (in-place over query buffer): wave stages its own Q before writing.
__global__ __launch_bounds__(256) void attn_kernel(const ushort_t* qin,
        const ushort_t* kvin, ushort_t* outp) {
    __shared__ ushort_t sm[4 * 3072];
    int wave = threadIdx.x >> 6, lane = threadIdx.x & 63;
    size_t p = (size_t)blockIdx.x * 4 + wave;
    ushort_t* sQ = sm + wave * 3072;
    ushort_t* sKV = sQ + 1024;
    const ushort_t* qp  = qin  + p * 1024;
    const ushort_t* kvp = kvin + p * 2048;
    *(ushort8*)(sQ + lane * 8)       = *(const ushort8*)(qp + lane * 8);
    *(ushort8*)(sQ + 512 + lane * 8) = *(const ushort8*)(qp + 512 + lane * 8);
    #pragma unroll
    for (int s = 0; s < 4; ++s)
        *(ushort8*)(sKV + s * 512 + lane * 8) = *(const ushort8*)(kvp + s * 512 + lane * 8);
    __syncthreads();
    int h = lane >> 3;
    int g = lane & 7;
    float sc = 0.f;
    #pragma unroll
    for (int j = 0; j < 128; j += 8) {
        ushort8 a = *(const ushort8*)(sQ + h * 128 + j);
        ushort8 k = *(const ushort8*)(sKV + g * 128 + j);
        #pragma unroll
        for (int t = 0; t < 8; ++t) sc += b2f(a[t]) * b2f(k[t]);
    }
    sc *= 0.08838834764831845f;   // 128^-0.5
    float mx = sc;
    mx = fmaxf(mx, __shfl_xor(mx, 1, 64));
    mx = fmaxf(mx, __shfl_xor(mx, 2, 64));
    mx = fmaxf(mx, __shfl_xor(mx, 4, 64));
    float e = __expf(sc - mx);
    float den = e;
    den += __shfl_xor(den, 1, 64);
    den += __shfl_xor(den, 2, 64);
    den += __shfl_xor(den, 4, 64);
    float w = e / den;
    int d0 = (lane & 7) * 16;
    int gb = lane & 56;
    float accv[16];
    #pragma unroll
    for (int t = 0; t < 16; ++t) accv[t] = 0.f;
    #pragma unroll
    for (int gg = 0; gg < 8; ++gg) {
        float wg = __shfl(w, gb + gg, 64);
        const ushort_t* vr = sKV + 1024 + gg * 128 + d0;
        ushort8 x0 = *(const ushort8*)(vr);
        ushort8 x1 = *(const ushort8*)(vr + 8);
        #pragma unroll
        for (int t = 0; t < 8; ++t) {
            accv[t]     += wg * b2f(x0[t]);
            accv[8 + t] += wg * b2f(x1[t]);
        }
    }
    ushort8 o0, o1;
    #pragma unroll
    for (int t = 0; t < 8; ++t) { o0[t] = f2b(accv[t]); o1[t] = f2b(accv[8 + t]); }
    ushort_t* op = outp + p * 1024 + h * 128 + d0;
    *(ushort8*)(op)     = o0;
    *(ushort8*)(op + 8) = o1;
}

extern "C" void kernel_launch(void* const* d_in, const int* in_sizes, int n_in,
                              void* d_out, int out_size, void* d_ws, size_t ws_size,
                              hipStream_t stream) {
    const float* q   = (const float*)d_in[0];
    const float* kv  = (const float*)d_in[1];
    const float* gm  = (const float*)d_in[2];
    const float* bm  = (const float*)d_in[3];
    const float* gl  = (const float*)d_in[4];
    const float* bl  = (const float*)d_in[5];
    const float* Wq  = (const float*)d_in[6];
    const float* Wkv = (const float*)d_in[7];
    const float* Wo  = (const float*)d_in[8];
    float* out = (float*)d_out;

    const int ROWS = 16 * 2048;           // 32768
    ushort_t* ws     = (ushort_t*)d_ws;
    ushort_t* norm   = ws;                                   // 64 MB: kvn, then qn (bf16)
    ushort_t* kvproj = norm + (size_t)ROWS * 1024;           // 128 MB: [ROWS, 2048] bf16
    ushort_t* qbuf   = kvproj + (size_t)ROWS * 2048;         // 64 MB: query, then context (bf16)
    ushort_t* wq_b   = qbuf + (size_t)ROWS * 1024;           // 2 MB
    ushort_t* wkv_b  = wq_b + 1024 * 1024;                   // 4 MB
    ushort_t* wo_b   = wkv_b + 2048 * 1024;                  // 2 MB

    // 0) weights fp32 -> bf16 (single launch, 4096 blocks)
    cvt_kernel<<<4096, 256, 0, stream>>>(Wq, Wkv, Wo, wq_b, wkv_b, wo_b);
    // 1) LN(kv) -> norm
    ln_kernel<<<ROWS / 4, 256, 0, stream>>>(kv, gl, bl, norm);
    // 2) norm @ Wkv^T -> kvproj  [ROWS, 2048]
    gemm256<false><<<dim3(2048 / 256, ROWS / 256), 512, 0, stream>>>(norm, wkv_b, kvproj, ROWS, 2048, 1024);
    // 3) LN(q) -> norm (kvn dead)
    ln_kernel<<<ROWS / 4, 256, 0, stream>>>(q, gm, bm, norm);
    // 4) norm @ Wq^T -> qbuf  [ROWS, 1024]
    gemm256<false><<<dim3(1024 / 256, ROWS / 256), 512, 0, stream>>>(norm, wq_b, qbuf, ROWS, 1024, 1024);
    // 5) attention per position, context written in place over qbuf
    attn_kernel<<<ROWS / 4, 256, 0, stream>>>(qbuf, kvproj, qbuf);
    // 6) context @ Wo^T -> out (fp32)
    gemm256<true><<<dim3(1024 / 256, ROWS / 256), 512, 0, stream>>>(qbuf, wo_b, out, ROWS, 1024, 1024);
}

// Round 2
// 660.798 us; speedup vs baseline: 1.0254x; 1.0254x over previous
//
#include <hip/hip_runtime.h>

typedef unsigned short ushort_t;
typedef __attribute__((ext_vector_type(4))) unsigned short ushort4_t;
typedef __attribute__((ext_vector_type(8))) unsigned short ushort8;
typedef __attribute__((ext_vector_type(8))) __bf16 bf16x8;
typedef __attribute__((ext_vector_type(4))) float f32x4;

typedef const unsigned int __attribute__((address_space(1)))* gas_ptr;
typedef unsigned int __attribute__((address_space(3)))* las_ptr;

__device__ __forceinline__ float b2f(unsigned short u) {
    union { unsigned int i; float f; } x; x.i = ((unsigned int)u) << 16; return x.f;
}
__device__ __forceinline__ unsigned short f2b(float f) {
    union { float f; unsigned int i; } x; x.f = f;
    unsigned int r = (x.i + 0x7fffu + ((x.i >> 16) & 1u)) >> 16;  // RNE
    return (unsigned short)r;
}

// ---------------- fp32 -> bf16 convert, all three weight mats in one launch ----------------
__global__ __launch_bounds__(256) void cvt_kernel(const float* __restrict__ wq,
        const float* __restrict__ wkv, const float* __restrict__ wo,
        ushort_t* __restrict__ yq, ushort_t* __restrict__ ykv, ushort_t* __restrict__ yo) {
    int b = blockIdx.x;
    const float* x; ushort_t* y; size_t off;
    if (b < 1024)      { x = wq;  y = yq;  off = (size_t)b * 1024; }
    else if (b < 3072) { x = wkv; y = ykv; off = (size_t)(b - 1024) * 1024; }
    else               { x = wo;  y = yo;  off = (size_t)(b - 3072) * 1024; }
    size_t i = off + threadIdx.x * 4;
    f32x4 v = *(const f32x4*)(x + i);
    ushort4_t o;
    #pragma unroll
    for (int t = 0; t < 4; ++t) o[t] = f2b(v[t]);
    *(ushort4_t*)(y + i) = o;
}

// ---------------- LayerNorm: one wave per 1024-elem row, fp32 in -> bf16 out ----------------
__global__ __launch_bounds__(256) void ln_kernel(const float* __restrict__ x,
        const float* __restrict__ gamma, const float* __restrict__ beta,
        ushort_t* __restrict__ y) {
    int wave = threadIdx.x >> 6, lane = threadIdx.x & 63;
    size_t row = (size_t)blockIdx.x * 4 + wave;
    const float* xr = x + row * 1024;
    f32x4 v[4];
    #pragma unroll
    for (int c = 0; c < 4; ++c) v[c] = *(const f32x4*)(xr + c * 256 + lane * 4);
    float s = 0.f, s2 = 0.f;
    #pragma unroll
    for (int c = 0; c < 4; ++c)
        #pragma unroll
        for (int t = 0; t < 4; ++t) { s += v[c][t]; s2 += v[c][t] * v[c][t]; }
    #pragma unroll
    for (int off = 1; off < 64; off <<= 1) {
        s  += __shfl_xor(s,  off, 64);
        s2 += __shfl_xor(s2, off, 64);
    }
    float mean = s * (1.0f / 1024.0f);
    float var  = fmaxf(s2 * (1.0f / 1024.0f) - mean * mean, 0.f);
    float rstd = rsqrtf(var + 1e-5f);
    ushort_t* yr = y + row * 1024;
    #pragma unroll
    for (int c = 0; c < 4; ++c) {
        f32x4 g = *(const f32x4*)(gamma + c * 256 + lane * 4);
        f32x4 b = *(const f32x4*)(beta  + c * 256 + lane * 4);
        ushort4_t o;
        #pragma unroll
        for (int t = 0; t < 4; ++t)
            o[t] = f2b((v[c][t] - mean) * rstd * g[t] + b[t]);
        *(ushort4_t*)(yr + c * 256 + lane * 4) = o;
    }
}

// ================== 256x256 8-phase GEMM: C[M,N] = A[M,K] * B[N,K]^T ==================
// 8-phase template (T1+T2+T3+T4+T5): BM=BN=256, BK=64, 512 thr (8 waves as 2Mx4N, each
// owns a 128x64 output = acc[8][4] f32x4). LDS = 2 buffers x (A[256][64]+B[256][64]) bf16
// = 128 KiB.
//
// T1 (round 2): bijective chunked XCD remap of the linear block id. HW round-robins
// linear wgs across 8 XCDs; remap nl=(lin&7)*(nwg/8)+(lin>>3) gives each XCD a
// contiguous chunk -> co-XCD blocks share A panels in that XCD's L2. Turns the A
// re-fetch (FETCH 270MB vs 68MB unique, r1) into L2 hits; mechanism here is latency
// (L2 ~200cy vs L3/HBM 450-900cy), since the vmcnt(4) pipe only covers ~2-3 phases.
// Requires nwg%8==0: holds (1024 / 512 wgs).
//
// T2: element (row,col) of a [*][64] tile stored at row*64 + (col ^ ((row&7)<<3)).
// global_load_lds writes linearly, so swizzle is realized by pre-swizzling the per-lane
// GLOBAL source column (both-sides-or-neither). Verified r1: SQ_LDS_BANK_CONFLICT = 0.
//
// Schedule per K-tile t (buf c = t&1), 4 phases; stage unit = 64 rows x 64 cols:
//   P0: stage A[64-127],A[192-255] of t+1 -> c^1 ; read A(qm=0)+B(qn=0) ; MFMA Q00
//   P1: stage B[128-191],B[192-255] of t+1 -> c^1 ; read B(qn=1)        ; MFMA Q01
//   P2: stage A[0-63],A[128-191] of t+2 -> c (qm=0 region retired at P0) ; MFMA Q10
//   P3: stage B[0-63],B[64-127]  of t+2 -> c (B retired after P1) ; MFMA Q11 ;
//       s_waitcnt vmcnt(4)  <-- round 2: AFTER the MFMAs, just before the closing
//       barrier (MFMA Q11 has no dep on these loads; buys ~1 phase more latency cover).
// vmcnt(4) accounting: 12 outstanding at the wait -> waits 8 oldest = tile t+1 fully
// landed; tile t+2's first 4 units stay in flight across the barrier (never drains to 0).
// Tail: staged kt clamped to K-64 (redundant L2-hit restage) so the count stays exact.
// Prologue: tile0 (8 units) -> buf0, tile1 u0-3 -> buf1, vmcnt(4), barrier. Needs K>=128.

#define STG_A(BUFB, RBASE, KT) \
    __builtin_amdgcn_global_load_lds((gas_ptr)(Ap + (size_t)(RBASE) * K + (KT)), \
        (las_ptr)(lds + (BUFB) * 32768 + (RBASE) * 64 + tid * 8), 16, 0, 0)
#define STG_B(BUFB, RBASE, KT) \
    __builtin_amdgcn_global_load_lds((gas_ptr)(Bp + (size_t)(RBASE) * K + (KT)), \
        (las_ptr)(lds + (BUFB) * 32768 + 16384 + (RBASE) * 64 + tid * 8), 16, 0, 0)

#define RD_A(CB, QM) do { _Pragma("unroll") \
    for (int fm = 0; fm < 4; ++fm) { \
        a[fm][0] = *(const bf16x8*)(lds + (CB) * 32768 + aB + (QM) * 4096 + fm * 1024 + ce0); \
        a[fm][1] = *(const bf16x8*)(lds + (CB) * 32768 + aB + (QM) * 4096 + fm * 1024 + ce1); \
    } } while (0)
#define RD_B(CB, QN, BV) do { _Pragma("unroll") \
    for (int fn = 0; fn < 2; ++fn) { \
        BV[fn][0] = *(const bf16x8*)(lds + (CB) * 32768 + bB + (QN) * 2048 + fn * 1024 + ce0); \
        BV[fn][1] = *(const bf16x8*)(lds + (CB) * 32768 + bB + (QN) * 2048 + fn * 1024 + ce1); \
    } } while (0)

#define MFMA_Q(QM, QN, BV) do { _Pragma("unroll") \
    for (int fm = 0; fm < 4; ++fm) { _Pragma("unroll") \
        for (int fn = 0; fn < 2; ++fn) { \
            acc[(QM) * 4 + fm][(QN) * 2 + fn] = __builtin_amdgcn_mfma_f32_16x16x32_bf16( \
                a[fm][0], BV[fn][0], acc[(QM) * 4 + fm][(QN) * 2 + fn], 0, 0, 0); \
            acc[(QM) * 4 + fm][(QN) * 2 + fn] = __builtin_amdgcn_mfma_f32_16x16x32_bf16( \
                a[fm][1], BV[fn][1], acc[(QM) * 4 + fm][(QN) * 2 + fn], 0, 0, 0); \
    } } } while (0)

#define PH_PRE() do { __builtin_amdgcn_s_barrier(); \
    asm volatile("s_waitcnt lgkmcnt(0)" ::: "memory"); \
    __builtin_amdgcn_s_setprio(1); } while (0)
#define PH_POST() do { __builtin_amdgcn_s_setprio(0); \
    __builtin_amdgcn_s_barrier(); } while (0)

#define KTILE(CB, KTN, KTNN) do { \
    /* P0 */ \
    STG_A((CB) ^ 1, 64, KTN); STG_A((CB) ^ 1, 192, KTN); \
    RD_A(CB, 0); RD_B(CB, 0, b0); \
    PH_PRE(); MFMA_Q(0, 0, b0); PH_POST(); \
    /* P1 */ \
    STG_B((CB) ^ 1, 128, KTN); STG_B((CB) ^ 1, 192, KTN); \
    RD_B(CB, 1, b1); \
    PH_PRE(); MFMA_Q(0, 1, b1); PH_POST(); \
    /* P2 */ \
    STG_A(CB, 0, KTNN); STG_A(CB, 128, KTNN); \
    RD_A(CB, 1); \
    PH_PRE(); MFMA_Q(1, 0, b0); PH_POST(); \
    /* P3 */ \
    STG_B(CB, 0, KTNN); STG_B(CB, 64, KTNN); \
    PH_PRE(); MFMA_Q(1, 1, b1); \
    __builtin_amdgcn_s_setprio(0); \
    asm volatile("s_waitcnt vmcnt(4)" ::: "memory"); \
    __builtin_amdgcn_s_barrier(); \
} while (0)

template <bool OUT_F32>
__global__ __launch_bounds__(512) void gemm256(const ushort_t* __restrict__ A,
        const ushort_t* __restrict__ B, void* __restrict__ Cv,
        int M, int N, int K) {
    __shared__ ushort_t lds[65536];   // 128 KiB
    const int tid = threadIdx.x;
    const int lane = tid & 63;
    const int wid = tid >> 6;
    const int wr = wid >> 2, wc = wid & 3;           // 2 (M) x 4 (N) wave grid
    const int r16 = lane & 15, q4 = lane >> 4;

    // T1: bijective chunked XCD remap (nwg % 8 == 0 for all our grids)
    const unsigned nwgx = gridDim.x;
    const unsigned lin = blockIdx.y * nwgx + blockIdx.x;
    const unsigned chunk = (nwgx * gridDim.y) >> 3;
    const unsigned nl = (lin & 7) * chunk + (lin >> 3);
    const int m0 = (int)(nl / nwgx) * 256, n0 = (int)(nl % nwgx) * 256;
    const int NT = K >> 6;

    // staging: thread handles one 16B chunk per unit; source col pre-swizzled
    const int rA = tid >> 3;                               // 0..63 within a unit
    const int cS = ((tid & 7) * 8) ^ ((rA & 7) * 8);       // inverse-swizzled src col
    const ushort_t* Ap = A + (size_t)(m0 + rA) * K + cS;
    const ushort_t* Bp = B + (size_t)(n0 + rA) * K + cS;

    // read-side swizzled column offsets (row&7 == lane&7 for every fragment row)
    const int ce0 = (q4 * 8) ^ ((lane & 7) * 8);           // kk=0
    const int ce1 = ce0 ^ 32;                              // kk=1
    const int aB = (wr * 128 + r16) * 64;                  // + qm*4096 + fm*1024
    const int bB = 16384 + (wc * 64 + r16) * 64;           // + qn*2048 + fn*1024

    f32x4 acc[8][4];
    #pragma unroll
    for (int i = 0; i < 8; ++i)
        #pragma unroll
        for (int j = 0; j < 4; ++j)
            acc[i][j] = (f32x4){0.f, 0.f, 0.f, 0.f};
    bf16x8 a[4][2], b0[2][2], b1[2][2];

    // prologue: tile0 (all 8 units) -> buf0 first (oldest), then tile1 u0-3 -> buf1
    STG_A(0, 0, 0); STG_A(0, 128, 0); STG_B(0, 0, 0); STG_B(0, 64, 0);
    STG_A(0, 64, 0); STG_A(0, 192, 0); STG_B(0, 128, 0); STG_B(0, 192, 0);
    STG_A(1, 0, 64); STG_A(1, 128, 64); STG_B(1, 0, 64); STG_B(1, 64, 64);
    asm volatile("s_waitcnt vmcnt(4)" ::: "memory");       // tile0 landed, tile1 u0-3 in flight
    __builtin_amdgcn_s_barrier();

    for (int tt = 0; tt < (NT >> 1); ++tt) {
        const int t = tt << 1;
        const int k1 = (t + 1) << 6;                       // always < K
        int k2 = (t + 2) << 6; if (k2 > K - 64) k2 = K - 64;
        int k3 = (t + 3) << 6; if (k3 > K - 64) k3 = K - 64;
        KTILE(0, k1, k2);
        KTILE(1, k2, k3);
    }

    // C/D: col = lane&15, row = (lane>>4)*4 + reg
    #pragma unroll
    for (int fm = 0; fm < 8; ++fm) {
        #pragma unroll
        for (int rr = 0; rr < 4; ++rr) {
            int rowC = m0 + wr * 128 + fm * 16 + q4 * 4 + rr;
            if (OUT_F32) {
                float* Cr = (float*)Cv + (size_t)rowC * N + n0 + wc * 64 + r16;
                #pragma unroll
                for (int fn = 0; fn < 4; ++fn)
                    Cr[fn * 16] = acc[fm][fn][rr];
            } else {
                ushort_t* Cr = (ushort_t*)Cv + (size_t)rowC * N + n0 + wc * 64 + r16;
                #pragma unroll
                for (int fn = 0; fn < 4; ++fn)
                    Cr[fn * 16] = f2b(acc[fm][fn][rr]);
            }
        }
    }
}

// ---------------- per-position 8x8 attention, one wave per position ----------------
// out may alias qin (in-place over query buffer): wave stages its own Q before writing.
__global__ __launch_bounds__(256) void attn_kernel(const ushort_t* qin,
        const ushort_t* kvin, ushort_t* outp) {
    __shared__ ushort_t sm[4 * 3072];
    int wave = threadIdx.x >> 6, lane = threadIdx.x & 63;
    size_t p = (size_t)blockIdx.x * 4 + wave;
    ushort_t* sQ = sm + wave * 3072;
    ushort_t* sKV = sQ + 1024;
    const ushort_t* qp  = qin  + p * 1024;
    const ushort_t* kvp = kvin + p * 2048;
    *(ushort8*)(sQ + lane * 8)       = *(const ushort8*)(qp + lane * 8);
    *(ushort8*)(sQ + 512 + lane * 8) = *(const ushort8*)(qp + 512 + lane * 8);
    #pragma unroll
    for (int s = 0; s < 4; ++s)
        *(ushort8*)(sKV + s * 512 + lane * 8) = *(const ushort8*)(kvp + s * 512 + lane * 8);
    __syncthreads();
    int h = lane >> 3;
    int g = lane & 7;
    float sc = 0.f;
    #pragma unroll
    for (int j = 0; j < 128; j += 8) {
        ushort8 a = *(const ushort8*)(sQ + h * 128 + j);
        ushort8 k = *(const ushort8*)(sKV + g * 128 + j);
        #pragma unroll
        for (int t = 0; t < 8; ++t) sc += b2f(a[t]) * b2f(k[t]);
    }
    sc *= 0.08838834764831845f;   // 128^-0.5
    float mx = sc;
    mx = fmaxf(mx, __shfl_xor(mx, 1, 64));
    mx = fmaxf(mx, __shfl_xor(mx, 2, 64));
    mx = fmaxf(mx, __shfl_xor(mx, 4, 64));
    float e = __expf(sc - mx);
    float den = e;
    den += __shfl_xor(den, 1, 64);
    den += __shfl_xor(den, 2, 64);
    den += __shfl_xor(den, 4, 64);
    float w = e / den;
    int d0 = (lane & 7) * 16;
    int gb = lane & 56;
    float accv[16];
    #pragma unroll
    for (int t = 0; t < 16; ++t) accv[t] = 0.f;
    #pragma unroll
    for (int gg = 0; gg < 8; ++gg) {
        float wg = __shfl(w, gb + gg, 64);
        const ushort_t* vr = sKV + 1024 + gg * 128 + d0;
        ushort8 x0 = *(const ushort8*)(vr);
        ushort8 x1 = *(const ushort8*)(vr + 8);
        #pragma unroll
        for (int t = 0; t < 8; ++t) {
            accv[t]     += wg * b2f(x0[t]);
            accv[8 + t] += wg * b2f(x1[t]);
        }
    }
    ushort8 o0, o1;
    #pragma unroll
    for (int t = 0; t < 8; ++t) { o0[t] = f2b(accv[t]); o1[t] = f2b(accv[8 + t]); }
    ushort_t* op = outp + p * 1024 + h * 128 + d0;
    *(ushort8*)(op)     = o0;
    *(ushort8*)(op + 8) = o1;
}

extern "C" void kernel_launch(void* const* d_in, const int* in_sizes, int n_in,
                              void* d_out, int out_size, void* d_ws, size_t ws_size,
                              hipStream_t stream) {
    const float* q   = (const float*)d_in[0];
    const float* kv  = (const float*)d_in[1];
    const float* gm  = (const float*)d_in[2];
    const float* bm  = (const float*)d_in[3];
    const float* gl  = (const float*)d_in[4];
    const float* bl  = (const float*)d_in[5];
    const float* Wq  = (const float*)d_in[6];
    const float* Wkv = (const float*)d_in[7];
    const float* Wo  = (const float*)d_in[8];
    float* out = (float*)d_out;

    const int ROWS = 16 * 2048;           // 32768
    ushort_t* ws     = (ushort_t*)d_ws;
    ushort_t* norm   = ws;                                   // 64 MB: kvn, then qn (bf16)
    ushort_t* kvproj = norm + (size_t)ROWS * 1024;           // 128 MB: [ROWS, 2048] bf16
    ushort_t* qbuf   = kvproj + (size_t)ROWS * 2048;         // 64 MB: query, then context (bf16)
    ushort_t* wq_b   = qbuf + (size_t)ROWS * 1024;           // 2 MB
    ushort_t* wkv_b  = wq_b + 1024 * 1024;                   // 4 MB
    ushort_t* wo_b   = wkv_b + 2048 * 1024;                  // 2 MB

    // 0) weights fp32 -> bf16 (single launch, 4096 blocks)
    cvt_kernel<<<4096, 256, 0, stream>>>(Wq, Wkv, Wo, wq_b, wkv_b, wo_b);
    // 1) LN(kv) -> norm
    ln_kernel<<<ROWS / 4, 256, 0, stream>>>(kv, gl, bl, norm);
    // 2) norm @ Wkv^T -> kvproj  [ROWS, 2048]
    gemm256<false><<<dim3(2048 / 256, ROWS / 256), 512, 0, stream>>>(norm, wkv_b, kvproj, ROWS, 2048, 1024);
    // 3) LN(q) -> norm (kvn dead)
    ln_kernel<<<ROWS / 4, 256, 0, stream>>>(q, gm, bm, norm);
    // 4) norm @ Wq^T -> qbuf  [ROWS, 1024]
    gemm256<false><<<dim3(1024 / 256, ROWS / 256), 512, 0, stream>>>(norm, wq_b, qbuf, ROWS, 1024, 1024);
    // 5) attention per position, context written in place over qbuf
    attn_kernel<<<ROWS / 4, 256, 0, stream>>>(qbuf, kvproj, qbuf);
    // 6) context @ Wo^T -> out (fp32)
    gemm256<true><<<dim3(1024 / 256, ROWS / 256), 512, 0, stream>>>(qbuf, wo_b, out, ROWS, 1024, 1024);
}

// Round 3
// 635.485 us; speedup vs baseline: 1.0663x; 1.0398x over previous
//
#include <hip/hip_runtime.h>

typedef unsigned short ushort_t;
typedef __attribute__((ext_vector_type(4))) unsigned short ushort4_t;
typedef __attribute__((ext_vector_type(8))) unsigned short ushort8;
typedef __attribute__((ext_vector_type(8))) __bf16 bf16x8;
typedef __attribute__((ext_vector_type(4))) float f32x4;

typedef const unsigned int __attribute__((address_space(1)))* gas_ptr;
typedef unsigned int __attribute__((address_space(3)))* las_ptr;

__device__ __forceinline__ float b2f(unsigned short u) {
    union { unsigned int i; float f; } x; x.i = ((unsigned int)u) << 16; return x.f;
}
__device__ __forceinline__ unsigned short f2b(float f) {
    union { float f; unsigned int i; } x; x.f = f;
    unsigned int r = (x.i + 0x7fffu + ((x.i >> 16) & 1u)) >> 16;  // RNE
    return (unsigned short)r;
}

// ---------------- fp32 -> bf16 convert, all three weight mats in one launch ----------------
__global__ __launch_bounds__(256) void cvt_kernel(const float* __restrict__ wq,
        const float* __restrict__ wkv, const float* __restrict__ wo,
        ushort_t* __restrict__ yq, ushort_t* __restrict__ ykv, ushort_t* __restrict__ yo) {
    int b = blockIdx.x;
    const float* x; ushort_t* y; size_t off;
    if (b < 1024)      { x = wq;  y = yq;  off = (size_t)b * 1024; }
    else if (b < 3072) { x = wkv; y = ykv; off = (size_t)(b - 1024) * 1024; }
    else               { x = wo;  y = yo;  off = (size_t)(b - 3072) * 1024; }
    size_t i = off + threadIdx.x * 4;
    f32x4 v = *(const f32x4*)(x + i);
    ushort4_t o;
    #pragma unroll
    for (int t = 0; t < 4; ++t) o[t] = f2b(v[t]);
    *(ushort4_t*)(y + i) = o;
}

// ---------------- LayerNorm: one wave per 1024-elem row, fp32 in -> bf16 out ----------------
__global__ __launch_bounds__(256) void ln_kernel(const float* __restrict__ x,
        const float* __restrict__ gamma, const float* __restrict__ beta,
        ushort_t* __restrict__ y) {
    int wave = threadIdx.x >> 6, lane = threadIdx.x & 63;
    size_t row = (size_t)blockIdx.x * 4 + wave;
    const float* xr = x + row * 1024;
    f32x4 v[4];
    #pragma unroll
    for (int c = 0; c < 4; ++c) v[c] = *(const f32x4*)(xr + c * 256 + lane * 4);
    float s = 0.f, s2 = 0.f;
    #pragma unroll
    for (int c = 0; c < 4; ++c)
        #pragma unroll
        for (int t = 0; t < 4; ++t) { s += v[c][t]; s2 += v[c][t] * v[c][t]; }
    #pragma unroll
    for (int off = 1; off < 64; off <<= 1) {
        s  += __shfl_xor(s,  off, 64);
        s2 += __shfl_xor(s2, off, 64);
    }
    float mean = s * (1.0f / 1024.0f);
    float var  = fmaxf(s2 * (1.0f / 1024.0f) - mean * mean, 0.f);
    float rstd = rsqrtf(var + 1e-5f);
    ushort_t* yr = y + row * 1024;
    #pragma unroll
    for (int c = 0; c < 4; ++c) {
        f32x4 g = *(const f32x4*)(gamma + c * 256 + lane * 4);
        f32x4 b = *(const f32x4*)(beta  + c * 256 + lane * 4);
        ushort4_t o;
        #pragma unroll
        for (int t = 0; t < 4; ++t)
            o[t] = f2b((v[c][t] - mean) * rstd * g[t] + b[t]);
        *(ushort4_t*)(yr + c * 256 + lane * 4) = o;
    }
}

// ================== persistent 256x256 8-phase GEMM: C[M,N] = A[M,K] * B[N,K]^T ==================
// Round 3: persistent blocks. Grid = exactly 256 (1 block/CU); each block loops over its
// 4 (N=2048) or 2 (N=1024) M-tiles, keeping the verified K-loop byte-identical. This removes
// the 4 sequential block-rounds of r2 (1 block/CU LDS => serial rounds; each paid a cold
// prologue + epilogue drain + dispatch gap; OccupancyPercent 20% < 25% structural = the
// signature). Iter boundary: exit-barrier -> vmcnt(0) (drain the 4 clamped-tail junk loads;
// needed because the prologue restages the SAME LDS lines and same-address load completions
// aren't ordered) -> issue next iter's 12 prologue stages -> C-write (stage latency hides
// under f2b+stores) -> vmcnt(4) -> barrier. The junk-staged regions == the prologue restage
// set exactly (checked region-by-region), so the buffer reset is clean.
//
// Placement (replaces r2's T1 remap, same bid&7=XCD assumption that r2 validated via the
// 2.75x FETCH drop): xcd=bid&7, j=bid>>3; n0=(j%nx)*256 constant per block (B panel L2-
// resident across iters); m0 walks 32/nx panels per iter, so an XCD's 32 blocks share 4
// A-panels at any time. nx=N/256 in {8,4}; M must be 32768 (16 m-tiles per XCD).
//
// T2 swizzle unchanged (r1: SQ_LDS_BANK_CONFLICT == 0). Schedule per K-tile unchanged
// (4 phases, counted vmcnt(4) at P3 after the MFMAs, never drains to 0 in the loop).

#define STG_AP(P, BUFB, RBASE, KT) \
    __builtin_amdgcn_global_load_lds((gas_ptr)((P) + (size_t)(RBASE) * K + (KT)), \
        (las_ptr)(lds + (BUFB) * 32768 + (RBASE) * 64 + tid * 8), 16, 0, 0)
#define STG_BP(BUFB, RBASE, KT) \
    __builtin_amdgcn_global_load_lds((gas_ptr)(Bp + (size_t)(RBASE) * K + (KT)), \
        (las_ptr)(lds + (BUFB) * 32768 + 16384 + (RBASE) * 64 + tid * 8), 16, 0, 0)
#define STG_A(BUFB, RBASE, KT) STG_AP(Ap, BUFB, RBASE, KT)
#define STG_B(BUFB, RBASE, KT) STG_BP(BUFB, RBASE, KT)

// prologue/restage set: all 8 units of buf0 (tile k=KA), first 4 of buf1 (tile k=KA+64)
#define PROLOGUE(P, KA) do { \
    STG_AP(P, 0, 0, KA); STG_AP(P, 0, 128, KA); STG_BP(0, 0, KA); STG_BP(0, 64, KA); \
    STG_AP(P, 0, 64, KA); STG_AP(P, 0, 192, KA); STG_BP(0, 128, KA); STG_BP(0, 192, KA); \
    STG_AP(P, 1, 0, (KA) + 64); STG_AP(P, 1, 128, (KA) + 64); \
    STG_BP(1, 0, (KA) + 64); STG_BP(1, 64, (KA) + 64); \
} while (0)

#define RD_A(CB, QM) do { _Pragma("unroll") \
    for (int fm = 0; fm < 4; ++fm) { \
        a[fm][0] = *(const bf16x8*)(lds + (CB) * 32768 + aB + (QM) * 4096 + fm * 1024 + ce0); \
        a[fm][1] = *(const bf16x8*)(lds + (CB) * 32768 + aB + (QM) * 4096 + fm * 1024 + ce1); \
    } } while (0)
#define RD_B(CB, QN, BV) do { _Pragma("unroll") \
    for (int fn = 0; fn < 2; ++fn) { \
        BV[fn][0] = *(const bf16x8*)(lds + (CB) * 32768 + bB + (QN) * 2048 + fn * 1024 + ce0); \
        BV[fn][1] = *(const bf16x8*)(lds + (CB) * 32768 + bB + (QN) * 2048 + fn * 1024 + ce1); \
    } } while (0)

#define MFMA_Q(QM, QN, BV) do { _Pragma("unroll") \
    for (int fm = 0; fm < 4; ++fm) { _Pragma("unroll") \
        for (int fn = 0; fn < 2; ++fn) { \
            acc[(QM) * 4 + fm][(QN) * 2 + fn] = __builtin_amdgcn_mfma_f32_16x16x32_bf16( \
                a[fm][0], BV[fn][0], acc[(QM) * 4 + fm][(QN) * 2 + fn], 0, 0, 0); \
            acc[(QM) * 4 + fm][(QN) * 2 + fn] = __builtin_amdgcn_mfma_f32_16x16x32_bf16( \
                a[fm][1], BV[fn][1], acc[(QM) * 4 + fm][(QN) * 2 + fn], 0, 0, 0); \
    } } } while (0)

#define PH_PRE() do { __builtin_amdgcn_s_barrier(); \
    asm volatile("s_waitcnt lgkmcnt(0)" ::: "memory"); \
    __builtin_amdgcn_s_setprio(1); } while (0)
#define PH_POST() do { __builtin_amdgcn_s_setprio(0); \
    __builtin_amdgcn_s_barrier(); } while (0)

#define KTILE(CB, KTN, KTNN) do { \
    /* P0 */ \
    STG_A((CB) ^ 1, 64, KTN); STG_A((CB) ^ 1, 192, KTN); \
    RD_A(CB, 0); RD_B(CB, 0, b0); \
    PH_PRE(); MFMA_Q(0, 0, b0); PH_POST(); \
    /* P1 */ \
    STG_B((CB) ^ 1, 128, KTN); STG_B((CB) ^ 1, 192, KTN); \
    RD_B(CB, 1, b1); \
    PH_PRE(); MFMA_Q(0, 1, b1); PH_POST(); \
    /* P2 */ \
    STG_A(CB, 0, KTNN); STG_A(CB, 128, KTNN); \
    RD_A(CB, 1); \
    PH_PRE(); MFMA_Q(1, 0, b0); PH_POST(); \
    /* P3 */ \
    STG_B(CB, 0, KTNN); STG_B(CB, 64, KTNN); \
    PH_PRE(); MFMA_Q(1, 1, b1); \
    __builtin_amdgcn_s_setprio(0); \
    asm volatile("s_waitcnt vmcnt(4)" ::: "memory"); \
    __builtin_amdgcn_s_barrier(); \
} while (0)

template <bool OUT_F32>
__global__ __launch_bounds__(512) void gemm256(const ushort_t* __restrict__ A,
        const ushort_t* __restrict__ B, void* __restrict__ Cv,
        int M, int N, int K) {
    __shared__ ushort_t lds[65536];   // 128 KiB
    const int tid = threadIdx.x;
    const int lane = tid & 63;
    const int wid = tid >> 6;
    const int wr = wid >> 2, wc = wid & 3;           // 2 (M) x 4 (N) wave grid
    const int r16 = lane & 15, q4 = lane >> 4;

    // persistent placement: xcd = bid&7, j = bid>>3 (0..31 within XCD)
    const int bid = blockIdx.x;
    const int xcd = bid & 7, j = bid >> 3;
    const int nx = N >> 8;                           // 8 or 4
    const int lnx = (nx == 8) ? 3 : 2;
    const int iters = nx >> 1;                       // 4 or 2
    const int n0 = (j & (nx - 1)) * 256;             // constant per block
    const int NT = K >> 6;

    // staging lane geometry: thread handles one 16B chunk per unit; source col pre-swizzled
    const int rA = tid >> 3;                               // 0..63 within a unit
    const int cS = ((tid & 7) * 8) ^ ((rA & 7) * 8);       // inverse-swizzled src col
    const ushort_t* Bp = B + (size_t)(n0 + rA) * K + cS;   // constant across iters

    // read-side swizzled column offsets (row&7 == lane&7 for every fragment row)
    const int ce0 = (q4 * 8) ^ ((lane & 7) * 8);           // kk=0
    const int ce1 = ce0 ^ 32;                              // kk=1
    const int aB = (wr * 128 + r16) * 64;                  // + qm*4096 + fm*1024
    const int bB = 16384 + (wc * 64 + r16) * 64;           // + qn*2048 + fn*1024

    f32x4 acc[8][4];
    bf16x8 a[4][2], b0[2][2], b1[2][2];

    int m0 = ((xcd << 4) + (j >> lnx)) << 8;               // iter r=0
    const int dm0 = 256 << (5 - lnx);                      // m0 step per iter
    const ushort_t* Ap = A + (size_t)(m0 + rA) * K + cS;

    PROLOGUE(Ap, 0);
    asm volatile("s_waitcnt vmcnt(4)" ::: "memory");       // tile0 landed, tile1 u0-3 in flight
    __builtin_amdgcn_s_barrier();

    for (int r = 0; r < iters; ++r) {
        #pragma unroll
        for (int i = 0; i < 8; ++i)
            #pragma unroll
            for (int jj = 0; jj < 4; ++jj)
                acc[i][jj] = (f32x4){0.f, 0.f, 0.f, 0.f};

        for (int tt = 0; tt < (NT >> 1); ++tt) {
            const int t = tt << 1;
            const int k1 = (t + 1) << 6;                   // always < K
            int k2 = (t + 2) << 6; if (k2 > K - 64) k2 = K - 64;
            int k3 = (t + 3) << 6; if (k3 > K - 64) k3 = K - 64;
            KTILE(0, k1, k2);
            KTILE(1, k2, k3);
        }

        // ---- iteration boundary ----
        const bool more = (r + 1 < iters);
        // drain clamped-tail junk loads before restaging the same LDS lines
        asm volatile("s_waitcnt vmcnt(0)" ::: "memory");
        const ushort_t* ApN = Ap + (size_t)dm0 * K;
        if (more) PROLOGUE(ApN, 0);                        // next-iter stages fly under C-write

        // C/D: col = lane&15, row = (lane>>4)*4 + reg
        #pragma unroll
        for (int fm = 0; fm < 8; ++fm) {
            #pragma unroll
            for (int rr = 0; rr < 4; ++rr) {
                int rowC = m0 + wr * 128 + fm * 16 + q4 * 4 + rr;
                if (OUT_F32) {
                    float* Cr = (float*)Cv + (size_t)rowC * N + n0 + wc * 64 + r16;
                    #pragma unroll
                    for (int fn = 0; fn < 4; ++fn)
                        Cr[fn * 16] = acc[fm][fn][rr];
                } else {
                    ushort_t* Cr = (ushort_t*)Cv + (size_t)rowC * N + n0 + wc * 64 + r16;
                    #pragma unroll
                    for (int fn = 0; fn < 4; ++fn)
                        Cr[fn * 16] = f2b(acc[fm][fn][rr]);
                }
            }
        }
        if (more) {
            m0 += dm0;
            Ap = ApN;
            asm volatile("s_waitcnt vmcnt(4)" ::: "memory");  // waits stores + 8 oldest loads
            __builtin_amdgcn_s_barrier();
        }
    }
}

// ---------------- per-position 8x8 attention, one wave per position ----------------
// out may alias qin (in-place over query buffer): wave stages its own Q before writing.
// LDS slices are wave-private -> no __syncthreads needed (intra-wave ds ordering is
// compiler-tracked via lgkmcnt).
__global__ __launch_bounds__(256) void attn_kernel(const ushort_t* qin,
        const ushort_t* kvin, ushort_t* outp) {
    __shared__ ushort_t sm[4 * 3072];
    int wave = threadIdx.x >> 6, lane = threadIdx.x & 63;
    size_t p = (size_t)blockIdx.x * 4 + wave;
    ushort_t* sQ = sm + wave * 3072;
    ushort_t* sKV = sQ + 1024;
    const ushort_t* qp  = qin  + p * 1024;
    const ushort_t* kvp = kvin + p * 2048;
    *(ushort8*)(sQ + lane * 8)       = *(const ushort8*)(qp + lane * 8);
    *(ushort8*)(sQ + 512 + lane * 8) = *(const ushort8*)(qp + 512 + lane * 8);
    #pragma unroll
    for (int s = 0; s < 4; ++s)
        *(ushort8*)(sKV + s * 512 + lane * 8) = *(const ushort8*)(kvp + s * 512 + lane * 8);
    int h = lane >> 3;
    int g = lane & 7;
    float sc = 0.f;
    #pragma unroll
    for (int jv = 0; jv < 128; jv += 8) {
        ushort8 aq = *(const ushort8*)(sQ + h * 128 + jv);
        ushort8 kq = *(const ushort8*)(sKV + g * 128 + jv);
        #pragma unroll
        for (int t = 0; t < 8; ++t) sc += b2f(aq[t]) * b2f(kq[t]);
    }
    sc *= 0.08838834764831845f;   // 128^-0.5
    float mx = sc;
    mx = fmaxf(mx, __shfl_xor(mx, 1, 64));
    mx = fmaxf(mx, __shfl_xor(mx, 2, 64));
    mx = fmaxf(mx, __shfl_xor(mx, 4, 64));
    float e = __expf(sc - mx);
    float den = e;
    den += __shfl_xor(den, 1, 64);
    den += __shfl_xor(den, 2, 64);
    den += __shfl_xor(den, 4, 64);
    float w = e / den;
    int d0 = (lane & 7) * 16;
    int gb = lane & 56;
    float accv[16];
    #pragma unroll
    for (int t = 0; t < 16; ++t) accv[t] = 0.f;
    #pragma unroll
    for (int gg = 0; gg < 8; ++gg) {
        float wg = __shfl(w, gb + gg, 64);
        const ushort_t* vr = sKV + 1024 + gg * 128 + d0;
        ushort8 x0 = *(const ushort8*)(vr);
        ushort8 x1 = *(const ushort8*)(vr + 8);
        #pragma unroll
        for (int t = 0; t < 8; ++t) {
            accv[t]     += wg * b2f(x0[t]);
            accv[8 + t] += wg * b2f(x1[t]);
        }
    }
    ushort8 o0, o1;
    #pragma unroll
    for (int t = 0; t < 8; ++t) { o0[t] = f2b(accv[t]); o1[t] = f2b(accv[8 + t]); }
    ushort_t* op = outp + p * 1024 + h * 128 + d0;
    *(ushort8*)(op)     = o0;
    *(ushort8*)(op + 8) = o1;
}

extern "C" void kernel_launch(void* const* d_in, const int* in_sizes, int n_in,
                              void* d_out, int out_size, void* d_ws, size_t ws_size,
                              hipStream_t stream) {
    const float* q   = (const float*)d_in[0];
    const float* kv  = (const float*)d_in[1];
    const float* gm  = (const float*)d_in[2];
    const float* bm  = (const float*)d_in[3];
    const float* gl  = (const float*)d_in[4];
    const float* bl  = (const float*)d_in[5];
    const float* Wq  = (const float*)d_in[6];
    const float* Wkv = (const float*)d_in[7];
    const float* Wo  = (const float*)d_in[8];
    float* out = (float*)d_out;

    const int ROWS = 16 * 2048;           // 32768
    ushort_t* ws     = (ushort_t*)d_ws;
    ushort_t* norm   = ws;                                   // 64 MB: kvn, then qn (bf16)
    ushort_t* kvproj = norm + (size_t)ROWS * 1024;           // 128 MB: [ROWS, 2048] bf16
    ushort_t* qbuf   = kvproj + (size_t)ROWS * 2048;         // 64 MB: query, then context (bf16)
    ushort_t* wq_b   = qbuf + (size_t)ROWS * 1024;           // 2 MB
    ushort_t* wkv_b  = wq_b + 1024 * 1024;                   // 4 MB
    ushort_t* wo_b   = wkv_b + 2048 * 1024;                  // 2 MB

    // 0) weights fp32 -> bf16 (single launch, 4096 blocks)
    cvt_kernel<<<4096, 256, 0, stream>>>(Wq, Wkv, Wo, wq_b, wkv_b, wo_b);
    // 1) LN(kv) -> norm
    ln_kernel<<<ROWS / 4, 256, 0, stream>>>(kv, gl, bl, norm);
    // 2) norm @ Wkv^T -> kvproj  [ROWS, 2048]  (persistent: 256 blocks, 4 iters)
    gemm256<false><<<256, 512, 0, stream>>>(norm, wkv_b, kvproj, ROWS, 2048, 1024);
    // 3) LN(q) -> norm (kvn dead)
    ln_kernel<<<ROWS / 4, 256, 0, stream>>>(q, gm, bm, norm);
    // 4) norm @ Wq^T -> qbuf  [ROWS, 1024]  (persistent: 256 blocks, 2 iters)
    gemm256<false><<<256, 512, 0, stream>>>(norm, wq_b, qbuf, ROWS, 1024, 1024);
    // 5) attention per position, context written in place over qbuf
    attn_kernel<<<ROWS / 4, 256, 0, stream>>>(qbuf, kvproj, qbuf);
    // 6) context @ Wo^T -> out (fp32)  (persistent: 256 blocks, 2 iters)
    gemm256<true><<<256, 512, 0, stream>>>(qbuf, wo_b, out, ROWS, 1024, 1024);
}